// Round 1
// baseline (103.447 us; speedup 1.0000x reference)
//
#include <hip/hip_runtime.h>

// Problem constants (from setup_inputs): B=64, H=W=384, P=1000.
#define BB 64
#define HH 384
#define WW 384
#define PP 1000
#define NITEMS (BB * PP)          // 64000 work items, one per (b, p)
#define NTERMS (NITEMS * 8)       // 512000 terms in the mean

__global__ __launch_bounds__(256)
void rd_loss_kernel(const float* __restrict__ pred,
                    const float* __restrict__ gt,
                    const int*   __restrict__ px,
                    const int*   __restrict__ py,
                    float* __restrict__ out) {
    const int idx = blockIdx.x * blockDim.x + threadIdx.x;
    float partial = 0.0f;
    if (idx < NITEMS) {
        const int b = idx / PP;
        const int p = idx - b * PP;
        const int x = px[p];
        const int y = py[p];
        const float* pb = pred + (size_t)b * (HH * WW);
        const float* gb = gt   + (size_t)b * (HH * WW);
        const int c = y * WW + x;
        const float pc = pb[c];
        const float gc = gb[c];
        // _DY = {-1,1,0,0,-1,-1,1,1}, _DX = {0,0,-1,1,-1,1,-1,1}
        const int off[8] = { c - WW, c + WW, c - 1, c + 1,
                             c - WW - 1, c - WW + 1, c + WW - 1, c + WW + 1 };
        float vp[8], vg[8];
        float sp = 0.0f, sg = 0.0f;
        #pragma unroll
        for (int i = 0; i < 8; ++i) {
            vp[i] = pc - pb[off[i]];
            vg[i] = gc - gb[off[i]];
            sp += vp[i] * vp[i];
            sg += vg[i] * vg[i];
        }
        float npn = sqrtf(sp); if (npn == 0.0f) npn = 1.0f;   // ref: norm==0 -> 1
        float ngn = sqrtf(sg); if (ngn == 0.0f) ngn = 1.0f;
        const float ip = 1.0f / npn;
        const float ig = 1.0f / ngn;
        float s = 0.0f;
        #pragma unroll
        for (int i = 0; i < 8; ++i)
            s += fabsf(vp[i] * ip - vg[i] * ig);
        partial = s;
    }

    // wave-64 shuffle reduction
    #pragma unroll
    for (int o = 32; o > 0; o >>= 1)
        partial += __shfl_down(partial, o, 64);

    __shared__ float wsum[4];     // 256 threads = 4 waves
    const int lane = threadIdx.x & 63;
    const int wid  = threadIdx.x >> 6;
    if (lane == 0) wsum[wid] = partial;
    __syncthreads();
    if (threadIdx.x == 0) {
        float t = wsum[0] + wsum[1] + wsum[2] + wsum[3];
        atomicAdd(out, t * (1.0f / (float)NTERMS));
    }
}

extern "C" void kernel_launch(void* const* d_in, const int* in_sizes, int n_in,
                              void* d_out, int out_size, void* d_ws, size_t ws_size,
                              hipStream_t stream) {
    const float* pred = (const float*)d_in[0];
    const float* gt   = (const float*)d_in[1];
    const int*   px   = (const int*)d_in[2];
    const int*   py   = (const int*)d_in[3];
    float* out = (float*)d_out;

    // d_out is re-poisoned to 0xAA before every launch; zero it for the atomics.
    hipMemsetAsync(out, 0, sizeof(float), stream);

    const int block = 256;
    const int grid = (NITEMS + block - 1) / block;   // 250 blocks
    rd_loss_kernel<<<grid, block, 0, stream>>>(pred, gt, px, py, out);
}